// Round 6
// baseline (151.824 us; speedup 1.0000x reference)
//
#include <hip/hip_runtime.h>
#include <math.h>

#define N_ROWS 262144
#define D 256
#define C 1000
#define CAP 512                          // per-class list capacity (E[n]=262, 6 sigma ~ 360)
#define TILE 32
#define NTILE 32                         // ceil(C/TILE)
#define NPAIR (NTILE * (NTILE + 1) / 2)  // 528 triangular tile pairs

typedef float f4v __attribute__((ext_vector_type(4)));

// ---------------- init: zero counters, min = +inf, done = 0 ----------------
__global__ void k_init(int* __restrict__ cnt, unsigned int* __restrict__ minb,
                       unsigned int* __restrict__ done) {
    int t = threadIdx.x;
    cnt[t] = 0;  // 1024 threads cover C=1000
    if (t == 0) *minb = 0x7f800000u;
    if (t == 1) *done = 0u;
}

// ---------------- build per-class row lists (one pass, global atomics) ----------------
__global__ void k_build(const int4* __restrict__ lab4, int* __restrict__ cnt,
                        int* __restrict__ list) {
    int i = blockIdx.x * 256 + threadIdx.x;  // 0..65535
    int4 l = lab4[i];
    int base = i * 4;
    list[l.x * CAP + atomicAdd(&cnt[l.x], 1)] = base;
    list[l.y * CAP + atomicAdd(&cnt[l.y], 1)] = base + 1;
    list[l.z * CAP + atomicAdd(&cnt[l.z], 1)] = base + 2;
    list[l.w * CAP + atomicAdd(&cnt[l.w], 1)] = base + 3;
}

// ---------------- per-class gather -> mean -> L2-normalize ----------------
// 1 block (512 thr = 8 waves) per class; wave w handles list rows w, w+8, ...
__global__ __launch_bounds__(512) void k_centroid(
    const float* __restrict__ feat, const int* __restrict__ list,
    const int* __restrict__ cnt, float* __restrict__ mn) {
    int c = blockIdx.x;
    int tid = threadIdx.x;
    int w = tid >> 6;    // wave 0..7
    int cg_ = tid & 63;  // float4 column group
    int n = cnt[c];
    int nl = (n < CAP) ? n : CAP;

    __shared__ int srow[CAP];
    for (int i = tid; i < nl; i += 512) srow[i] = list[c * CAP + i];
    __syncthreads();

    f4v acc = {0.f, 0.f, 0.f, 0.f};
    int r = w;
    for (; r + 56 < nl; r += 64) {
        int rows[8];
        #pragma unroll
        for (int u = 0; u < 8; ++u) rows[u] = srow[r + u * 8];
        f4v v[8];
        #pragma unroll
        for (int u = 0; u < 8; ++u)
            v[u] = reinterpret_cast<const f4v*>(feat + (size_t)rows[u] * D)[cg_];
        #pragma unroll
        for (int u = 0; u < 8; ++u) acc += v[u];
    }
    for (; r < nl; r += 8) {
        int row = srow[r];
        acc += reinterpret_cast<const f4v*>(feat + (size_t)row * D)[cg_];
    }

    __shared__ f4v part[8][64];
    part[w][cg_] = acc;
    __syncthreads();
    if (w == 0) {
        f4v t = {0.f, 0.f, 0.f, 0.f};
        #pragma unroll
        for (int i = 0; i < 8; ++i) t += part[i][cg_];
        float inv = 1.0f / fmaxf((float)n, 1.0f);
        f4v mean = t * inv;
        float ss = mean.x * mean.x + mean.y * mean.y + mean.z * mean.z + mean.w * mean.w;
        #pragma unroll
        for (int o = 32; o; o >>= 1) ss += __shfl_down(ss, o, 64);
        ss = __shfl(ss, 0, 64);
        float rn = rsqrtf(ss);
        f4v o4 = mean * rn;
        reinterpret_cast<f4v*>(mn + (size_t)c * D)[cg_] = o4;
    }
}

// ---------------- min off-diagonal cosine distance (triangular tiles, fused final) ----
__global__ __launch_bounds__(256) void k_mindist(
    const float* __restrict__ mn, unsigned int* __restrict__ minb,
    unsigned int* __restrict__ done, float* __restrict__ out) {
    int t = blockIdx.x;
    int bi = 0;
    while (t >= NTILE - bi) { t -= NTILE - bi; ++bi; }
    int bj = bi + t;
    int i0 = bi * TILE, j0 = bj * TILE;

    __shared__ float A[TILE * D];
    __shared__ float B[TILE * D];
    float4* A4 = reinterpret_cast<float4*>(A);
    float4* B4 = reinterpret_cast<float4*>(B);
    int tid = threadIdx.x;

    for (int k = tid; k < TILE * (D / 4); k += 256) {
        int r = k >> 6;       // row in tile
        int g = k & 63;       // float4 group
        int sg = g ^ ((r >> 1) & 7);
        int gi = i0 + r, gj = j0 + r;
        float4 z = make_float4(0.f, 0.f, 0.f, 0.f);
        A4[r * 64 + sg] = (gi < C) ? reinterpret_cast<const float4*>(mn + (size_t)gi * D)[g] : z;
        B4[r * 64 + sg] = (gj < C) ? reinterpret_cast<const float4*>(mn + (size_t)gj * D)[g] : z;
    }
    __syncthreads();

    int ti = tid >> 4, tj = tid & 15;
    int il = ti * 2, jl = tj * 2;
    int sa = ti & 7;
    int sb = tj & 7;

    float a00 = 0.f, a01 = 0.f, a10 = 0.f, a11 = 0.f;
    #pragma unroll 4
    for (int g = 0; g < 64; ++g) {
        float4 x0 = A4[il * 64 + (g ^ sa)];
        float4 x1 = A4[(il + 1) * 64 + (g ^ sa)];
        float4 y0 = B4[jl * 64 + (g ^ sb)];
        float4 y1 = B4[(jl + 1) * 64 + (g ^ sb)];
        a00 += x0.x * y0.x + x0.y * y0.y + x0.z * y0.z + x0.w * y0.w;
        a01 += x0.x * y1.x + x0.y * y1.y + x0.z * y1.z + x0.w * y1.w;
        a10 += x1.x * y0.x + x1.y * y0.y + x1.z * y0.z + x1.w * y0.w;
        a11 += x1.x * y1.x + x1.y * y1.y + x1.z * y1.z + x1.w * y1.w;
    }

    float m = INFINITY;
    int gi0 = i0 + il, gj0 = j0 + jl;
    if (gi0 < C && gj0 < C && gi0 != gj0)         m = fminf(m, 1.f - fminf(fmaxf(a00, -1.f), 1.f));
    if (gi0 < C && gj0 + 1 < C && gi0 != gj0 + 1) m = fminf(m, 1.f - fminf(fmaxf(a01, -1.f), 1.f));
    if (gi0 + 1 < C && gj0 < C && gi0 + 1 != gj0) m = fminf(m, 1.f - fminf(fmaxf(a10, -1.f), 1.f));
    if (gi0 + 1 < C && gj0 + 1 < C && gi0 != gj0) m = fminf(m, 1.f - fminf(fmaxf(a11, -1.f), 1.f));

    #pragma unroll
    for (int o = 32; o; o >>= 1) m = fminf(m, __shfl_down(m, o, 64));
    if ((tid & 63) == 0) atomicMin(minb, __float_as_uint(m));

    __syncthreads();
    if (tid == 0) {
        __threadfence();
        unsigned int old = atomicAdd(done, 1u);
        if (old == (unsigned int)(gridDim.x - 1)) {
            float d = __uint_as_float(atomicOr(minb, 0u));
            out[0] = logf(1.0f / (d + 1e-6f) + 1.0f);
        }
    }
}

extern "C" void kernel_launch(void* const* d_in, const int* in_sizes, int n_in,
                              void* d_out, int out_size, void* d_ws, size_t ws_size,
                              hipStream_t stream) {
    const float* feat   = (const float*)d_in[0];
    const int*   labels = (const int*)d_in[1];
    float* out = (float*)d_out;

    int*      cnt  = (int*)d_ws;                 // [1024]
    int*      list = cnt + 1024;                 // [C*CAP]
    float*    mnrm = (float*)(list + C * CAP);   // [C*D]
    unsigned* minb = (unsigned*)(mnrm + C * D);  // [1]
    unsigned* done = minb + 1;                   // [1]

    k_init<<<1, 1024, 0, stream>>>(cnt, minb, done);
    k_build<<<N_ROWS / 4 / 256, 256, 0, stream>>>((const int4*)labels, cnt, list);
    k_centroid<<<C, 512, 0, stream>>>(feat, list, cnt, mnrm);
    k_mindist<<<NPAIR, 256, 0, stream>>>(mnrm, minb, done, out);
}